// Round 13
// baseline (2518.767 us; speedup 1.0000x reference)
//
#include <hip/hip_runtime.h>

#define S_ 160
#define B_ 64
#define H_ 1024
#define E_ 512
#define V_ 64
#define T_ 16
#define H4_ 4096

__device__ __forceinline__ float sigm(float x) { return 1.f / (1.f + expf(-x)); }

// ---------------------------------------------------------------------------
// enc_t = enc_out @ enc_W^T + enc_b.  128x128 tile, BK=16, 8x8 acc/thread.
// (validated round 8)
// ---------------------------------------------------------------------------
__global__ __launch_bounds__(256) void gemm_bt_128(
    const float* __restrict__ A, const float* __restrict__ Bm,
    const float* __restrict__ bias, float* __restrict__ Cd,
    int M, int N, int K)
{
    __shared__ float As[16][132];
    __shared__ float Bs[16][132];
    const int bn = blockIdx.x, bm = blockIdx.y;
    const int tid = threadIdx.x;
    const int lr = tid >> 1, lk = (tid & 1) * 8;
    const int tx4 = (tid & 15) * 4, ty4 = (tid >> 4) * 4;
    const float* Ap = A + (size_t)(bm * 128 + lr) * K + lk;
    const float* Bp = Bm + (size_t)(bn * 128 + lr) * K + lk;
    float acc[8][8] = {};
    for (int k0 = 0; k0 < K; k0 += 16) {
        float4 a0 = *(const float4*)(Ap + k0);
        float4 a1 = *(const float4*)(Ap + k0 + 4);
        float4 b0 = *(const float4*)(Bp + k0);
        float4 b1 = *(const float4*)(Bp + k0 + 4);
        __syncthreads();
        As[lk + 0][lr] = a0.x; As[lk + 1][lr] = a0.y; As[lk + 2][lr] = a0.z; As[lk + 3][lr] = a0.w;
        As[lk + 4][lr] = a1.x; As[lk + 5][lr] = a1.y; As[lk + 6][lr] = a1.z; As[lk + 7][lr] = a1.w;
        Bs[lk + 0][lr] = b0.x; Bs[lk + 1][lr] = b0.y; Bs[lk + 2][lr] = b0.z; Bs[lk + 3][lr] = b0.w;
        Bs[lk + 4][lr] = b1.x; Bs[lk + 5][lr] = b1.y; Bs[lk + 6][lr] = b1.z; Bs[lk + 7][lr] = b1.w;
        __syncthreads();
#pragma unroll
        for (int kk = 0; kk < 16; ++kk) {
            float a[8], b[8];
            *(float4*)(a)     = *(const float4*)&As[kk][ty4];
            *(float4*)(a + 4) = *(const float4*)&As[kk][64 + ty4];
            *(float4*)(b)     = *(const float4*)&Bs[kk][tx4];
            *(float4*)(b + 4) = *(const float4*)&Bs[kk][64 + tx4];
#pragma unroll
            for (int i = 0; i < 8; ++i)
#pragma unroll
                for (int j = 0; j < 8; ++j) acc[i][j] = fmaf(a[i], b[j], acc[i][j]);
        }
    }
#pragma unroll
    for (int i = 0; i < 8; ++i) {
        int row = bm * 128 + ((i < 4) ? (ty4 + i) : (64 + ty4 + i - 4));
#pragma unroll
        for (int j = 0; j < 8; ++j) {
            int col = bn * 128 + ((j < 4) ? (tx4 + j) : (64 + tx4 + j - 4));
            Cd[(size_t)row * N + col] = acc[i][j] + bias[col];
        }
    }
}

// 64x64 tile GEMM helper (BK=16). Arow/Brow already offset by (lr*ld + lc).
__device__ __forceinline__ void tile64(const float* __restrict__ Arow,
                                       const float* __restrict__ Brow,
                                       int K, float acc[4][4],
                                       float* __restrict__ As,
                                       float* __restrict__ Bs)
{
    const int tid = threadIdx.x;
    const int lr = tid >> 2, lc = (tid & 3) << 2;
    const int tx = tid & 15, ty = tid >> 4;
    for (int k0 = 0; k0 < K; k0 += 16) {
        float4 av = *(const float4*)(Arow + k0);
        float4 bv = *(const float4*)(Brow + k0);
        __syncthreads();
        As[lr * 17 + lc + 0] = av.x; As[lr * 17 + lc + 1] = av.y;
        As[lr * 17 + lc + 2] = av.z; As[lr * 17 + lc + 3] = av.w;
        Bs[lr * 17 + lc + 0] = bv.x; Bs[lr * 17 + lc + 1] = bv.y;
        Bs[lr * 17 + lc + 2] = bv.z; Bs[lr * 17 + lc + 3] = bv.w;
        __syncthreads();
#pragma unroll
        for (int kk = 0; kk < 16; ++kk) {
            float a[4], b[4];
#pragma unroll
            for (int i = 0; i < 4; ++i) a[i] = As[(ty * 4 + i) * 17 + kk];
#pragma unroll
            for (int j = 0; j < 4; ++j) b[j] = Bs[(tx * 4 + j) * 17 + kk];
#pragma unroll
            for (int i = 0; i < 4; ++i)
#pragma unroll
                for (int j = 0; j < 4; ++j) acc[i][j] = fmaf(a[i], b[j], acc[i][j]);
        }
    }
    __syncthreads();
}

// Split-K partials: Cpart[kz][M][N] (validated). KS==1 -> plain GEMM to Cpart.
__global__ __launch_bounds__(256) void gemm_part(
    const float* __restrict__ A, const float* __restrict__ Bm,
    float* __restrict__ Cpart, int M, int N, int K)
{
    __shared__ float smem[2176];
    const int bn = blockIdx.x, bm = blockIdx.y, kz = blockIdx.z, KS = gridDim.z;
    const int tid = threadIdx.x;
    const int lr = tid >> 2, lc = (tid & 3) << 2;
    const int tx = tid & 15, ty = tid >> 4;
    const int kLen = K / KS, k0base = kz * kLen;
    float acc[4][4] = {};
    tile64(A + (size_t)(bm * 64 + lr) * K + k0base + lc,
           Bm + (size_t)(bn * 64 + lr) * K + k0base + lc,
           kLen, acc, smem, smem + 1088);
    float* Cp = Cpart + (size_t)kz * M * N;
#pragma unroll
    for (int i = 0; i < 4; ++i) {
        int row = bm * 64 + ty * 4 + i;
#pragma unroll
        for (int j = 0; j < 4; ++j)
            Cp[(size_t)row * N + bn * 64 + tx * 4 + j] = acc[i][j];
    }
}

__global__ void reduce_partials(const float* __restrict__ Cpart, int KS,
                                const float* __restrict__ bias,
                                const float* __restrict__ bias2,
                                float* __restrict__ C, int MN, int N)
{
    int idx = blockIdx.x * 256 + threadIdx.x;
    if (idx >= MN) return;
    float v = 0.f;
    for (int z = 0; z < KS; ++z) v += Cpart[(size_t)z * MN + idx];
    int col = idx % N;
    if (bias)  v += bias[col];
    if (bias2) v += bias2[col];
    C[idx] = v;
}

// Build emb_ext (rows 0..63 = embed, row 64 = tok_emb, 65..127 = 0);
// zero negent/logp accumulators.
__global__ void init_k(const float* __restrict__ embed, const float* __restrict__ tok_emb,
                       float* __restrict__ emb_ext,
                       float* __restrict__ negent, float* __restrict__ logp)
{
    int i = blockIdx.x * 256 + threadIdx.x;
    if (i < 128 * E_) {
        int r = i >> 9, c = i & (E_ - 1);
        emb_ext[i] = (r < 64) ? embed[r * E_ + c] : ((r == 64) ? tok_emb[c] : 0.f);
    }
    if (i < B_) { negent[i] = 0.f; logp[i] = 0.f; }
}

// ---------------------------------------------------------------------------
// Fused LSTM + dec split-K GEMM. Grid (16,1,4) = 64 blocks (bn, kz).
// Phase A: parallel LSTM of the A-tile [64 b][256 hh] into LDS — all
// addresses AFFINE in (b, h) (no data-dependent indices; the R10 pitfall).
// gsrc/strideB: t==0 -> SOS row of all_gates (stride 0); t>0 -> gates_sel.
// bn==0 blocks publish out_h. Phase B: tile64-style GEMM, A from LDS.
// ---------------------------------------------------------------------------
__global__ __launch_bounds__(256) void lstm_dec_k(
    const float* __restrict__ gsrc, size_t strideB,
    const float* __restrict__ hh_gates, const float* __restrict__ enc_c0,
    const float* __restrict__ dec_W,
    float* __restrict__ out_h, float* __restrict__ dec_part)
{
    __shared__ float Ah[64][257];
    __shared__ float Bs[64][17];
    const int tid = threadIdx.x;
    const int bn = blockIdx.x, kz = blockIdx.z;
    const int k0base = kz * 256;
    const int h = k0base + tid;
    // ---- Phase A: LSTM for all 64 b rows of this kz-slice ----
#pragma unroll 4
    for (int b = 0; b < 64; ++b) {
        const float* ag = gsrc + (size_t)b * strideB;
        const float* hg = hh_gates + (size_t)b * H4_;
        float gi = ag[h]          + hg[h];
        float gf = ag[H_ + h]     + hg[H_ + h];
        float gg = ag[2 * H_ + h] + hg[2 * H_ + h];
        float go = ag[3 * H_ + h] + hg[3 * H_ + h];
        float cc = sigm(gf) * enc_c0[(size_t)b * H_ + h] + sigm(gi) * tanhf(gg);
        float oh = sigm(go) * tanhf(cc);
        Ah[b][tid] = oh;
        if (bn == 0) out_h[(size_t)b * H_ + h] = oh;
    }
    __syncthreads();
    // ---- Phase B: 64x64 GEMM tile, A from LDS, B staged from dec_W ----
    const int lr = tid >> 2, lc = (tid & 3) << 2;
    const int tx = tid & 15, ty = tid >> 4;
    const float* Bp = dec_W + (size_t)(bn * 64 + lr) * H_ + k0base + lc;
    float acc[4][4] = {};
    for (int k0 = 0; k0 < 256; k0 += 16) {
        float4 bv = *(const float4*)(Bp + k0);
        __syncthreads();
        Bs[lr][lc] = bv.x; Bs[lr][lc + 1] = bv.y;
        Bs[lr][lc + 2] = bv.z; Bs[lr][lc + 3] = bv.w;
        __syncthreads();
#pragma unroll
        for (int kk = 0; kk < 16; ++kk) {
            float a[4], b4[4];
#pragma unroll
            for (int i = 0; i < 4; ++i) a[i] = Ah[ty * 4 + i][k0 + kk];
#pragma unroll
            for (int j = 0; j < 4; ++j) b4[j] = Bs[tx * 4 + j][kk];
#pragma unroll
            for (int i = 0; i < 4; ++i)
#pragma unroll
                for (int j = 0; j < 4; ++j) acc[i][j] = fmaf(a[i], b4[j], acc[i][j]);
        }
    }
    float* Cp = dec_part + (size_t)kz * B_ * H_;
#pragma unroll
    for (int i = 0; i < 4; ++i)
#pragma unroll
        for (int j = 0; j < 4; ++j)
            Cp[(size_t)(ty * 4 + i) * H_ + bn * 64 + tx * 4 + j] = acc[i][j];
}

// ---------------------------------------------------------------------------
// Attention scores: 512 blocks x 4 waves = 2048 waves; wave (b, sg) does 5 s.
// dec partial-sum (KS=4) + dec_b folded in registers. (validated round 8)
// ---------------------------------------------------------------------------
__global__ __launch_bounds__(256) void score_k(
    const float* __restrict__ enc_t, const float* __restrict__ dec_part,
    const float* __restrict__ dec_b, const float* __restrict__ attn_W,
    const float* __restrict__ attn_b, const int* __restrict__ lens,
    float* __restrict__ scores)
{
    const int lane = threadIdx.x & 63;
    const int gw = blockIdx.x * 4 + (threadIdx.x >> 6);   // 0..2047
    const int b = gw >> 5, sg = gw & 31;                  // 32 waves/b, 5 s each
    float dec_r[16], aw_r[16];
#pragma unroll
    for (int it = 0; it < 16; ++it) {
        int h = lane + it * 64;
        dec_r[it] = dec_part[(size_t)b * H_ + h]
                  + dec_part[(size_t)(B_ + b) * H_ + h]
                  + dec_part[(size_t)(2 * B_ + b) * H_ + h]
                  + dec_part[(size_t)(3 * B_ + b) * H_ + h]
                  + dec_b[h];
        aw_r[it] = attn_W[h];
    }
    const int len = lens[b];
    const float ab = attn_b[0];
    for (int s = sg * 5; s < sg * 5 + 5; ++s) {
        if (s >= len) { if (lane == 0) scores[b * S_ + s] = -1e9f; continue; }
        const float* ep = enc_t + ((size_t)s * B_ + b) * H_;
        float acc = 0.f;
#pragma unroll
        for (int it = 0; it < 16; ++it)
            acc += aw_r[it] * tanhf(ep[lane + it * 64] + dec_r[it]);
        for (int d = 32; d; d >>= 1) acc += __shfl_xor(acc, d);
        if (lane == 0) scores[b * S_ + s] = acc + ab;
    }
}

// ---------------------------------------------------------------------------
// Fused: softmax + attn-map out + context (float4, len-bounded) + logits +
// softmax/renorm + argmax + stats + VALUE-gather of next gate row.
// One block per b. (validated round 12; context loop now len-bounded)
// ---------------------------------------------------------------------------
__global__ __launch_bounds__(256) void smax_out_k(
    const float* __restrict__ scores, const float* __restrict__ enc_out,
    const float* __restrict__ out_h, const float* __restrict__ out_W,
    const float* __restrict__ out_b, const float* __restrict__ all_gates,
    const int* __restrict__ lens, float* __restrict__ gates_sel,
    float* __restrict__ negent_acc, float* __restrict__ logp_acc,
    float* __restrict__ out, int t)
{
    __shared__ float sc[S_];
    __shared__ float comb[2 * H_];
    __shared__ float lg[V_];
    __shared__ int tok_s;
    const int tid = threadIdx.x;
    const int b = blockIdx.x;
    const int lane = tid & 63, wv = tid >> 6;
    if (wv == 0) {
        float m = -1e30f;
        for (int s = lane; s < S_; s += 64) {
            float v = scores[b * S_ + s]; sc[s] = v; m = fmaxf(m, v);
        }
        for (int d = 32; d; d >>= 1) m = fmaxf(m, __shfl_xor(m, d));
        float sum = 0.f;
        for (int s = lane; s < S_; s += 64) {
            float e = expf(sc[s] - m); sc[s] = e; sum += e;
        }
        for (int d = 32; d; d >>= 1) sum += __shfl_xor(sum, d);
        float inv = 1.f / sum;
        for (int s = lane; s < S_; s += 64) {
            float pr = sc[s] * inv; sc[s] = pr;
            out[T_ * B_ + ((size_t)b * T_ + t) * S_ + s] = pr;
        }
    }
    __syncthreads();
    {   // context: 4 h per thread, float4, 4-way ILP, bounded by len
        const int len4 = (lens[b] + 3) & ~3;
        const float* base = enc_out + (size_t)b * H_ + tid * 4;
        float4 ac0 = {0,0,0,0}, ac1 = {0,0,0,0}, ac2 = {0,0,0,0}, ac3 = {0,0,0,0};
        for (int s = 0; s < len4; s += 4) {
            float4 e0 = *(const float4*)(base + (size_t)(s    ) * B_ * H_);
            float4 e1 = *(const float4*)(base + (size_t)(s + 1) * B_ * H_);
            float4 e2 = *(const float4*)(base + (size_t)(s + 2) * B_ * H_);
            float4 e3 = *(const float4*)(base + (size_t)(s + 3) * B_ * H_);
            float p0 = sc[s], p1 = sc[s + 1], p2 = sc[s + 2], p3 = sc[s + 3];
            ac0.x = fmaf(p0, e0.x, ac0.x); ac0.y = fmaf(p0, e0.y, ac0.y);
            ac0.z = fmaf(p0, e0.z, ac0.z); ac0.w = fmaf(p0, e0.w, ac0.w);
            ac1.x = fmaf(p1, e1.x, ac1.x); ac1.y = fmaf(p1, e1.y, ac1.y);
            ac1.z = fmaf(p1, e1.z, ac1.z); ac1.w = fmaf(p1, e1.w, ac1.w);
            ac2.x = fmaf(p2, e2.x, ac2.x); ac2.y = fmaf(p2, e2.y, ac2.y);
            ac2.z = fmaf(p2, e2.z, ac2.z); ac2.w = fmaf(p2, e2.w, ac2.w);
            ac3.x = fmaf(p3, e3.x, ac3.x); ac3.y = fmaf(p3, e3.y, ac3.y);
            ac3.z = fmaf(p3, e3.z, ac3.z); ac3.w = fmaf(p3, e3.w, ac3.w);
        }
        comb[tid * 4 + 0] = ac0.x + ac1.x + ac2.x + ac3.x;
        comb[tid * 4 + 1] = ac0.y + ac1.y + ac2.y + ac3.y;
        comb[tid * 4 + 2] = ac0.z + ac1.z + ac2.z + ac3.z;
        comb[tid * 4 + 3] = ac0.w + ac1.w + ac2.w + ac3.w;
    }
    for (int i = tid; i < H_; i += 256) comb[H_ + i] = out_h[(size_t)b * H_ + i];
    __syncthreads();
    for (int v = wv * 16; v < wv * 16 + 16; ++v) {
        const float* w = out_W + (size_t)v * (2 * H_);
        float a0 = 0.f, a1 = 0.f;
#pragma unroll
        for (int j = 0; j < 32; j += 2) {
            a0 = fmaf(comb[lane + j * 64], w[lane + j * 64], a0);
            a1 = fmaf(comb[lane + (j + 1) * 64], w[lane + (j + 1) * 64], a1);
        }
        float acc = a0 + a1;
        for (int d = 32; d; d >>= 1) acc += __shfl_xor(acc, d);
        if (lane == 0) lg[v] = acc + out_b[v];
    }
    __syncthreads();
    if (wv == 0) {
        float x = lg[lane];
        float m = x;
        for (int d = 32; d; d >>= 1) m = fmaxf(m, __shfl_xor(m, d));
        float e = expf(x - m);
        float s = e;
        for (int d = 32; d; d >>= 1) s += __shfl_xor(s, d);
        float pr = e / s;
        float ps = pr;
        for (int d = 32; d; d >>= 1) ps += __shfl_xor(ps, d);
        pr = pr / ps;   // reference renormalizes
        float bv = pr; int bi = lane;
        for (int d = 32; d; d >>= 1) {
            float ov = __shfl_xor(bv, d); int oi = __shfl_xor(bi, d);
            if (ov > bv || (ov == bv && oi < bi)) { bv = ov; bi = oi; }
        }
        float ne = pr * logf(pr + 1e-6f);
        for (int d = 32; d; d >>= 1) ne += __shfl_xor(ne, d);
        float ptok = __shfl(pr, bi);
        if (lane == 0) {
            out[t * B_ + b] = (float)bi;
            float na = negent_acc[b] + ne;                negent_acc[b] = na;
            float la = logp_acc[b] + logf(ptok + 1e-6f);  logp_acc[b] = la;
            if (t == T_ - 1) {
                out[T_ * B_ + B_ * T_ * S_ + b] = na;
                out[T_ * B_ + B_ * T_ * S_ + B_ + b] = la;
            }
            tok_s = bi;
        }
    }
    __syncthreads();
    {   // value-gather: gates_sel[b] = all_gates[tok_s]  (4096 floats, float4)
        const int tk = tok_s;
        const float4* src = (const float4*)(all_gates + (size_t)tk * H4_);
        float4* dst = (float4*)(gates_sel + (size_t)b * H4_);
        for (int i = tid; i < H4_ / 4; i += 256) dst[i] = src[i];
    }
}

extern "C" void kernel_launch(void* const* d_in, const int* in_sizes, int n_in,
                              void* d_out, int out_size, void* d_ws, size_t ws_size,
                              hipStream_t stream) {
    const float* enc_h0  = (const float*)d_in[0];
    const float* enc_c0  = (const float*)d_in[1];
    const float* enc_out = (const float*)d_in[2];
    const int*   lens    = (const int*)d_in[3];
    const float* tok_emb = (const float*)d_in[4];
    const float* embed   = (const float*)d_in[5];
    const float* W_ih    = (const float*)d_in[6];
    const float* W_hh    = (const float*)d_in[7];
    const float* b_ih    = (const float*)d_in[8];
    const float* b_hh    = (const float*)d_in[9];
    const float* out_W   = (const float*)d_in[10];
    const float* out_b   = (const float*)d_in[11];
    const float* enc_W   = (const float*)d_in[12];
    const float* enc_b   = (const float*)d_in[13];
    const float* dec_W   = (const float*)d_in[14];
    const float* dec_b   = (const float*)d_in[15];
    const float* attn_W  = (const float*)d_in[16];
    const float* attn_b  = (const float*)d_in[17];
    float* out = (float*)d_out;

    // ws layout (floats). part aliases enc_t (consumed before enc_t written).
    float* ws = (float*)d_ws;
    float* hh_gates  = ws;                         // 262144
    float* out_h     = hh_gates + B_ * H4_;        // 65536
    float* dec_part  = out_h + B_ * H_;            // 262144
    float* scores    = dec_part + 4 * B_ * H_;     // 10240
    float* negent    = scores + B_ * S_;           // 64
    float* logp      = negent + B_;                // 64
    float* gates_sel = logp + B_;                  // 262144 (B x 4H)
    float* emb_ext   = gates_sel + B_ * H4_;       // 65536 (128 x 512)
    float* all_gates = emb_ext + 128 * E_;         // 524288 (128 x 4096)
    float* enc_t     = all_gates + (size_t)128 * H4_;  // 10485760
    float* part      = enc_t;                      // alias: 4 x B x 4H
    // total = 11,937,920 floats = 47,751,680 B (ws_size known >= 49,152,512)
    if (ws_size < 47751680u) return;

    init_k<<<(128 * E_ + 255) / 256, 256, 0, stream>>>(embed, tok_emb, emb_ext,
                                                       negent, logp);

    // hh_gates = h0 @ W_hh^T + b_ih + b_hh (step-invariant)
    gemm_part<<<dim3(H4_ / 64, 1, 4), 256, 0, stream>>>(enc_h0, W_hh, part, B_, H4_, H_);
    reduce_partials<<<(B_ * H4_ + 255) / 256, 256, 0, stream>>>(
        part, 4, b_ih, b_hh, hh_gates, B_ * H4_, H4_);

    // all_gates = emb_ext @ W_ih^T (no bias; biases live in hh_gates)
    gemm_part<<<dim3(H4_ / 64, 2, 1), 256, 0, stream>>>(emb_ext, W_ih, all_gates,
                                                        128, H4_, E_);

    // enc_t = encoder_outputs @ enc_W^T + enc_b (after part consumed)
    gemm_bt_128<<<dim3(H_ / 128, (S_ * B_) / 128), 256, 0, stream>>>(
        enc_out, enc_W, enc_b, enc_t, S_ * B_, H_, H_);

    for (int t = 0; t < T_; ++t) {
        const float* gsrc = (t == 0) ? (all_gates + (size_t)64 * H4_) : gates_sel;
        const size_t strideB = (t == 0) ? 0 : (size_t)H4_;
        lstm_dec_k<<<dim3(16, 1, 4), 256, 0, stream>>>(gsrc, strideB, hh_gates, enc_c0,
                                                       dec_W, out_h, dec_part);
        score_k<<<512, 256, 0, stream>>>(enc_t, dec_part, dec_b, attn_W, attn_b, lens, scores);
        smax_out_k<<<64, 256, 0, stream>>>(scores, enc_out, out_h, out_W, out_b,
                                           all_gates, lens, gates_sel, negent, logp, out, t);
    }
}

// Round 14
// 1785.217 us; speedup vs baseline: 1.4109x; 1.4109x over previous
//
#include <hip/hip_runtime.h>

#define S_ 160
#define B_ 64
#define H_ 1024
#define E_ 512
#define V_ 64
#define T_ 16
#define H4_ 4096

__device__ __forceinline__ float sigm(float x) { return 1.f / (1.f + expf(-x)); }

// ---------------------------------------------------------------------------
// enc_t = enc_out @ enc_W^T + enc_b.  128x128 tile, BK=16, 8x8 acc/thread,
// register-prefetch double buffering (loads for k0+16 in flight during k0's
// compute).
// ---------------------------------------------------------------------------
__global__ __launch_bounds__(256) void gemm_bt_128(
    const float* __restrict__ A, const float* __restrict__ Bm,
    const float* __restrict__ bias, float* __restrict__ Cd,
    int M, int N, int K)
{
    __shared__ float As[16][132];
    __shared__ float Bs[16][132];
    const int bn = blockIdx.x, bm = blockIdx.y;
    const int tid = threadIdx.x;
    const int lr = tid >> 1, lk = (tid & 1) * 8;
    const int tx4 = (tid & 15) * 4, ty4 = (tid >> 4) * 4;
    const float* Ap = A + (size_t)(bm * 128 + lr) * K + lk;
    const float* Bp = Bm + (size_t)(bn * 128 + lr) * K + lk;
    float4 a0 = *(const float4*)(Ap);
    float4 a1 = *(const float4*)(Ap + 4);
    float4 b0 = *(const float4*)(Bp);
    float4 b1 = *(const float4*)(Bp + 4);
    float acc[8][8] = {};
    for (int k0 = 0; k0 < K; k0 += 16) {
        __syncthreads();
        As[lk + 0][lr] = a0.x; As[lk + 1][lr] = a0.y; As[lk + 2][lr] = a0.z; As[lk + 3][lr] = a0.w;
        As[lk + 4][lr] = a1.x; As[lk + 5][lr] = a1.y; As[lk + 6][lr] = a1.z; As[lk + 7][lr] = a1.w;
        Bs[lk + 0][lr] = b0.x; Bs[lk + 1][lr] = b0.y; Bs[lk + 2][lr] = b0.z; Bs[lk + 3][lr] = b0.w;
        Bs[lk + 4][lr] = b1.x; Bs[lk + 5][lr] = b1.y; Bs[lk + 6][lr] = b1.z; Bs[lk + 7][lr] = b1.w;
        __syncthreads();
        if (k0 + 16 < K) {   // prefetch next k-tile while computing this one
            a0 = *(const float4*)(Ap + k0 + 16);
            a1 = *(const float4*)(Ap + k0 + 20);
            b0 = *(const float4*)(Bp + k0 + 16);
            b1 = *(const float4*)(Bp + k0 + 20);
        }
#pragma unroll
        for (int kk = 0; kk < 16; ++kk) {
            float a[8], b[8];
            *(float4*)(a)     = *(const float4*)&As[kk][ty4];
            *(float4*)(a + 4) = *(const float4*)&As[kk][64 + ty4];
            *(float4*)(b)     = *(const float4*)&Bs[kk][tx4];
            *(float4*)(b + 4) = *(const float4*)&Bs[kk][64 + tx4];
#pragma unroll
            for (int i = 0; i < 8; ++i)
#pragma unroll
                for (int j = 0; j < 8; ++j) acc[i][j] = fmaf(a[i], b[j], acc[i][j]);
        }
    }
#pragma unroll
    for (int i = 0; i < 8; ++i) {
        int row = bm * 128 + ((i < 4) ? (ty4 + i) : (64 + ty4 + i - 4));
#pragma unroll
        for (int j = 0; j < 8; ++j) {
            int col = bn * 128 + ((j < 4) ? (tx4 + j) : (64 + tx4 + j - 4));
            Cd[(size_t)row * N + col] = acc[i][j] + bias[col];
        }
    }
}

// 64x64 tile GEMM helper (BK=16). Arow/Brow already offset by (lr*ld + lc).
__device__ __forceinline__ void tile64(const float* __restrict__ Arow,
                                       const float* __restrict__ Brow,
                                       int K, float acc[4][4],
                                       float* __restrict__ As,
                                       float* __restrict__ Bs)
{
    const int tid = threadIdx.x;
    const int lr = tid >> 2, lc = (tid & 3) << 2;
    const int tx = tid & 15, ty = tid >> 4;
    for (int k0 = 0; k0 < K; k0 += 16) {
        float4 av = *(const float4*)(Arow + k0);
        float4 bv = *(const float4*)(Brow + k0);
        __syncthreads();
        As[lr * 17 + lc + 0] = av.x; As[lr * 17 + lc + 1] = av.y;
        As[lr * 17 + lc + 2] = av.z; As[lr * 17 + lc + 3] = av.w;
        Bs[lr * 17 + lc + 0] = bv.x; Bs[lr * 17 + lc + 1] = bv.y;
        Bs[lr * 17 + lc + 2] = bv.z; Bs[lr * 17 + lc + 3] = bv.w;
        __syncthreads();
#pragma unroll
        for (int kk = 0; kk < 16; ++kk) {
            float a[4], b[4];
#pragma unroll
            for (int i = 0; i < 4; ++i) a[i] = As[(ty * 4 + i) * 17 + kk];
#pragma unroll
            for (int j = 0; j < 4; ++j) b[j] = Bs[(tx * 4 + j) * 17 + kk];
#pragma unroll
            for (int i = 0; i < 4; ++i)
#pragma unroll
                for (int j = 0; j < 4; ++j) acc[i][j] = fmaf(a[i], b[j], acc[i][j]);
        }
    }
    __syncthreads();
}

// Split-K partials: Cpart[kz][M][N] (validated). KS==1 -> plain GEMM to Cpart.
__global__ __launch_bounds__(256) void gemm_part(
    const float* __restrict__ A, const float* __restrict__ Bm,
    float* __restrict__ Cpart, int M, int N, int K)
{
    __shared__ float smem[2176];
    const int bn = blockIdx.x, bm = blockIdx.y, kz = blockIdx.z, KS = gridDim.z;
    const int tid = threadIdx.x;
    const int lr = tid >> 2, lc = (tid & 3) << 2;
    const int tx = tid & 15, ty = tid >> 4;
    const int kLen = K / KS, k0base = kz * kLen;
    float acc[4][4] = {};
    tile64(A + (size_t)(bm * 64 + lr) * K + k0base + lc,
           Bm + (size_t)(bn * 64 + lr) * K + k0base + lc,
           kLen, acc, smem, smem + 1088);
    float* Cp = Cpart + (size_t)kz * M * N;
#pragma unroll
    for (int i = 0; i < 4; ++i) {
        int row = bm * 64 + ty * 4 + i;
#pragma unroll
        for (int j = 0; j < 4; ++j)
            Cp[(size_t)row * N + bn * 64 + tx * 4 + j] = acc[i][j];
    }
}

__global__ void reduce_partials(const float* __restrict__ Cpart, int KS,
                                const float* __restrict__ bias,
                                const float* __restrict__ bias2,
                                float* __restrict__ C, int MN, int N)
{
    int idx = blockIdx.x * 256 + threadIdx.x;
    if (idx >= MN) return;
    float v = 0.f;
    for (int z = 0; z < KS; ++z) v += Cpart[(size_t)z * MN + idx];
    int col = idx % N;
    if (bias)  v += bias[col];
    if (bias2) v += bias2[col];
    C[idx] = v;
}

// Build emb_ext (rows 0..63 = embed, row 64 = tok_emb, 65..127 = 0);
// zero negent/logp accumulators.
__global__ void init_k(const float* __restrict__ embed, const float* __restrict__ tok_emb,
                       float* __restrict__ emb_ext,
                       float* __restrict__ negent, float* __restrict__ logp)
{
    int i = blockIdx.x * 256 + threadIdx.x;
    if (i < 128 * E_) {
        int r = i >> 9, c = i & (E_ - 1);
        emb_ext[i] = (r < 64) ? embed[r * E_ + c] : ((r == 64) ? tok_emb[c] : 0.f);
    }
    if (i < B_) { negent[i] = 0.f; logp[i] = 0.f; }
}

// ---------------------------------------------------------------------------
// Fused LSTM + dec split-K GEMM, WIDE grid (16,4,4) = 256 blocks (bn,bq,kz).
// Phase A: LSTM for a 16(b) x 256(h) sub-tile -> 16 cells/thread serial
// (R13's failure was 64 cells/thread on 64 blocks). All addresses affine.
// bn==0 blocks publish out_h (each (bq,kz) slice exactly once).
// Phase B: 16x64 GEMM sub-tile, K=256, A from LDS, B staged from dec_W.
// ---------------------------------------------------------------------------
__global__ __launch_bounds__(256) void lstm_dec_k(
    const float* __restrict__ gsrc, size_t strideB,
    const float* __restrict__ hh_gates, const float* __restrict__ enc_c0,
    const float* __restrict__ dec_W,
    float* __restrict__ out_h, float* __restrict__ dec_part)
{
    __shared__ float Ah[16][257];
    __shared__ float Bs[64][17];
    const int tid = threadIdx.x;
    const int bn = blockIdx.x, bq = blockIdx.y, kz = blockIdx.z;
    const int k0base = kz * 256;
    // ---- Phase A ----
#pragma unroll 4
    for (int e = 0; e < 16; ++e) {
        int idx = e * 256 + tid;
        int bl = idx >> 8, hl = idx & 255;
        int b = bq * 16 + bl, h = k0base + hl;
        const float* ag = gsrc + (size_t)b * strideB;
        const float* hg = hh_gates + (size_t)b * H4_;
        float gi = ag[h]          + hg[h];
        float gf = ag[H_ + h]     + hg[H_ + h];
        float gg = ag[2 * H_ + h] + hg[2 * H_ + h];
        float go = ag[3 * H_ + h] + hg[3 * H_ + h];
        float cc = sigm(gf) * enc_c0[(size_t)b * H_ + h] + sigm(gi) * tanhf(gg);
        float oh = sigm(go) * tanhf(cc);
        Ah[bl][hl] = oh;
        if (bn == 0) out_h[(size_t)b * H_ + h] = oh;
    }
    __syncthreads();
    // ---- Phase B: rows r in {ty,ty+4,ty+8,ty+12}, col tx ----
    const int tx = tid & 63, ty = tid >> 6;
    const int sr = tid >> 2, sk = (tid & 3) * 4;
    float acc0 = 0.f, acc1 = 0.f, acc2 = 0.f, acc3 = 0.f;
    for (int k0 = 0; k0 < 256; k0 += 16) {
        float4 bv = *(const float4*)(dec_W + (size_t)(bn * 64 + sr) * H_ + k0base + k0 + sk);
        __syncthreads();
        Bs[sr][sk] = bv.x; Bs[sr][sk + 1] = bv.y;
        Bs[sr][sk + 2] = bv.z; Bs[sr][sk + 3] = bv.w;
        __syncthreads();
#pragma unroll
        for (int kk = 0; kk < 16; ++kk) {
            float b4 = Bs[tx][kk];
            acc0 = fmaf(Ah[ty     ][k0 + kk], b4, acc0);
            acc1 = fmaf(Ah[ty +  4][k0 + kk], b4, acc1);
            acc2 = fmaf(Ah[ty +  8][k0 + kk], b4, acc2);
            acc3 = fmaf(Ah[ty + 12][k0 + kk], b4, acc3);
        }
    }
    float* Cp = dec_part + (size_t)kz * B_ * H_;
    const int n = bn * 64 + tx;
    Cp[(size_t)(bq * 16 + ty     ) * H_ + n] = acc0;
    Cp[(size_t)(bq * 16 + ty +  4) * H_ + n] = acc1;
    Cp[(size_t)(bq * 16 + ty +  8) * H_ + n] = acc2;
    Cp[(size_t)(bq * 16 + ty + 12) * H_ + n] = acc3;
}

// ---------------------------------------------------------------------------
// Attention scores: 512 blocks x 4 waves = 2048 waves; wave (b, sg) does 5 s.
// dec partial-sum (KS=4) + dec_b folded in registers. (validated round 8)
// ---------------------------------------------------------------------------
__global__ __launch_bounds__(256) void score_k(
    const float* __restrict__ enc_t, const float* __restrict__ dec_part,
    const float* __restrict__ dec_b, const float* __restrict__ attn_W,
    const float* __restrict__ attn_b, const int* __restrict__ lens,
    float* __restrict__ scores)
{
    const int lane = threadIdx.x & 63;
    const int gw = blockIdx.x * 4 + (threadIdx.x >> 6);   // 0..2047
    const int b = gw >> 5, sg = gw & 31;                  // 32 waves/b, 5 s each
    float dec_r[16], aw_r[16];
#pragma unroll
    for (int it = 0; it < 16; ++it) {
        int h = lane + it * 64;
        dec_r[it] = dec_part[(size_t)b * H_ + h]
                  + dec_part[(size_t)(B_ + b) * H_ + h]
                  + dec_part[(size_t)(2 * B_ + b) * H_ + h]
                  + dec_part[(size_t)(3 * B_ + b) * H_ + h]
                  + dec_b[h];
        aw_r[it] = attn_W[h];
    }
    const int len = lens[b];
    const float ab = attn_b[0];
    for (int s = sg * 5; s < sg * 5 + 5; ++s) {
        if (s >= len) { if (lane == 0) scores[b * S_ + s] = -1e9f; continue; }
        const float* ep = enc_t + ((size_t)s * B_ + b) * H_;
        float acc = 0.f;
#pragma unroll
        for (int it = 0; it < 16; ++it)
            acc += aw_r[it] * tanhf(ep[lane + it * 64] + dec_r[it]);
        for (int d = 32; d; d >>= 1) acc += __shfl_xor(acc, d);
        if (lane == 0) scores[b * S_ + s] = acc + ab;
    }
}

// ---------------------------------------------------------------------------
// Fused: softmax + attn-map out + context (float4, len-bounded) + logits +
// softmax/renorm + argmax + stats + VALUE-gather of next gate row.
// One block per b. (validated rounds 12/13)
// ---------------------------------------------------------------------------
__global__ __launch_bounds__(256) void smax_out_k(
    const float* __restrict__ scores, const float* __restrict__ enc_out,
    const float* __restrict__ out_h, const float* __restrict__ out_W,
    const float* __restrict__ out_b, const float* __restrict__ all_gates,
    const int* __restrict__ lens, float* __restrict__ gates_sel,
    float* __restrict__ negent_acc, float* __restrict__ logp_acc,
    float* __restrict__ out, int t)
{
    __shared__ float sc[S_];
    __shared__ float comb[2 * H_];
    __shared__ float lg[V_];
    __shared__ int tok_s;
    const int tid = threadIdx.x;
    const int b = blockIdx.x;
    const int lane = tid & 63, wv = tid >> 6;
    if (wv == 0) {
        float m = -1e30f;
        for (int s = lane; s < S_; s += 64) {
            float v = scores[b * S_ + s]; sc[s] = v; m = fmaxf(m, v);
        }
        for (int d = 32; d; d >>= 1) m = fmaxf(m, __shfl_xor(m, d));
        float sum = 0.f;
        for (int s = lane; s < S_; s += 64) {
            float e = expf(sc[s] - m); sc[s] = e; sum += e;
        }
        for (int d = 32; d; d >>= 1) sum += __shfl_xor(sum, d);
        float inv = 1.f / sum;
        for (int s = lane; s < S_; s += 64) {
            float pr = sc[s] * inv; sc[s] = pr;
            out[T_ * B_ + ((size_t)b * T_ + t) * S_ + s] = pr;
        }
    }
    __syncthreads();
    {   // context: 4 h per thread, float4, 4-way ILP, bounded by len
        const int len4 = (lens[b] + 3) & ~3;
        const float* base = enc_out + (size_t)b * H_ + tid * 4;
        float4 ac0 = {0,0,0,0}, ac1 = {0,0,0,0}, ac2 = {0,0,0,0}, ac3 = {0,0,0,0};
        for (int s = 0; s < len4; s += 4) {
            float4 e0 = *(const float4*)(base + (size_t)(s    ) * B_ * H_);
            float4 e1 = *(const float4*)(base + (size_t)(s + 1) * B_ * H_);
            float4 e2 = *(const float4*)(base + (size_t)(s + 2) * B_ * H_);
            float4 e3 = *(const float4*)(base + (size_t)(s + 3) * B_ * H_);
            float p0 = sc[s], p1 = sc[s + 1], p2 = sc[s + 2], p3 = sc[s + 3];
            ac0.x = fmaf(p0, e0.x, ac0.x); ac0.y = fmaf(p0, e0.y, ac0.y);
            ac0.z = fmaf(p0, e0.z, ac0.z); ac0.w = fmaf(p0, e0.w, ac0.w);
            ac1.x = fmaf(p1, e1.x, ac1.x); ac1.y = fmaf(p1, e1.y, ac1.y);
            ac1.z = fmaf(p1, e1.z, ac1.z); ac1.w = fmaf(p1, e1.w, ac1.w);
            ac2.x = fmaf(p2, e2.x, ac2.x); ac2.y = fmaf(p2, e2.y, ac2.y);
            ac2.z = fmaf(p2, e2.z, ac2.z); ac2.w = fmaf(p2, e2.w, ac2.w);
            ac3.x = fmaf(p3, e3.x, ac3.x); ac3.y = fmaf(p3, e3.y, ac3.y);
            ac3.z = fmaf(p3, e3.z, ac3.z); ac3.w = fmaf(p3, e3.w, ac3.w);
        }
        comb[tid * 4 + 0] = ac0.x + ac1.x + ac2.x + ac3.x;
        comb[tid * 4 + 1] = ac0.y + ac1.y + ac2.y + ac3.y;
        comb[tid * 4 + 2] = ac0.z + ac1.z + ac2.z + ac3.z;
        comb[tid * 4 + 3] = ac0.w + ac1.w + ac2.w + ac3.w;
    }
    for (int i = tid; i < H_; i += 256) comb[H_ + i] = out_h[(size_t)b * H_ + i];
    __syncthreads();
    for (int v = wv * 16; v < wv * 16 + 16; ++v) {
        const float* w = out_W + (size_t)v * (2 * H_);
        float a0 = 0.f, a1 = 0.f;
#pragma unroll
        for (int j = 0; j < 32; j += 2) {
            a0 = fmaf(comb[lane + j * 64], w[lane + j * 64], a0);
            a1 = fmaf(comb[lane + (j + 1) * 64], w[lane + (j + 1) * 64], a1);
        }
        float acc = a0 + a1;
        for (int d = 32; d; d >>= 1) acc += __shfl_xor(acc, d);
        if (lane == 0) lg[v] = acc + out_b[v];
    }
    __syncthreads();
    if (wv == 0) {
        float x = lg[lane];
        float m = x;
        for (int d = 32; d; d >>= 1) m = fmaxf(m, __shfl_xor(m, d));
        float e = expf(x - m);
        float s = e;
        for (int d = 32; d; d >>= 1) s += __shfl_xor(s, d);
        float pr = e / s;
        float ps = pr;
        for (int d = 32; d; d >>= 1) ps += __shfl_xor(ps, d);
        pr = pr / ps;   // reference renormalizes
        float bv = pr; int bi = lane;
        for (int d = 32; d; d >>= 1) {
            float ov = __shfl_xor(bv, d); int oi = __shfl_xor(bi, d);
            if (ov > bv || (ov == bv && oi < bi)) { bv = ov; bi = oi; }
        }
        float ne = pr * logf(pr + 1e-6f);
        for (int d = 32; d; d >>= 1) ne += __shfl_xor(ne, d);
        float ptok = __shfl(pr, bi);
        if (lane == 0) {
            out[t * B_ + b] = (float)bi;
            float na = negent_acc[b] + ne;                negent_acc[b] = na;
            float la = logp_acc[b] + logf(ptok + 1e-6f);  logp_acc[b] = la;
            if (t == T_ - 1) {
                out[T_ * B_ + B_ * T_ * S_ + b] = na;
                out[T_ * B_ + B_ * T_ * S_ + B_ + b] = la;
            }
            tok_s = bi;
        }
    }
    __syncthreads();
    {   // value-gather: gates_sel[b] = all_gates[tok_s]  (4096 floats, float4)
        const int tk = tok_s;
        const float4* src = (const float4*)(all_gates + (size_t)tk * H4_);
        float4* dst = (float4*)(gates_sel + (size_t)b * H4_);
        for (int i = tid; i < H4_ / 4; i += 256) dst[i] = src[i];
    }
}

extern "C" void kernel_launch(void* const* d_in, const int* in_sizes, int n_in,
                              void* d_out, int out_size, void* d_ws, size_t ws_size,
                              hipStream_t stream) {
    const float* enc_h0  = (const float*)d_in[0];
    const float* enc_c0  = (const float*)d_in[1];
    const float* enc_out = (const float*)d_in[2];
    const int*   lens    = (const int*)d_in[3];
    const float* tok_emb = (const float*)d_in[4];
    const float* embed   = (const float*)d_in[5];
    const float* W_ih    = (const float*)d_in[6];
    const float* W_hh    = (const float*)d_in[7];
    const float* b_ih    = (const float*)d_in[8];
    const float* b_hh    = (const float*)d_in[9];
    const float* out_W   = (const float*)d_in[10];
    const float* out_b   = (const float*)d_in[11];
    const float* enc_W   = (const float*)d_in[12];
    const float* enc_b   = (const float*)d_in[13];
    const float* dec_W   = (const float*)d_in[14];
    const float* dec_b   = (const float*)d_in[15];
    const float* attn_W  = (const float*)d_in[16];
    const float* attn_b  = (const float*)d_in[17];
    float* out = (float*)d_out;

    // ws layout (floats). part aliases enc_t (consumed before enc_t written).
    float* ws = (float*)d_ws;
    float* hh_gates  = ws;                         // 262144
    float* out_h     = hh_gates + B_ * H4_;        // 65536
    float* dec_part  = out_h + B_ * H_;            // 262144
    float* scores    = dec_part + 4 * B_ * H_;     // 10240
    float* negent    = scores + B_ * S_;           // 64
    float* logp      = negent + B_;                // 64
    float* gates_sel = logp + B_;                  // 262144 (B x 4H)
    float* emb_ext   = gates_sel + B_ * H4_;       // 65536 (128 x 512)
    float* all_gates = emb_ext + 128 * E_;         // 524288 (128 x 4096)
    float* enc_t     = all_gates + (size_t)128 * H4_;  // 10485760
    float* part      = enc_t;                      // alias: 4 x B x 4H
    // total = 11,937,920 floats = 47,751,680 B (ws_size known >= 49,152,512)
    if (ws_size < 47751680u) return;

    init_k<<<(128 * E_ + 255) / 256, 256, 0, stream>>>(embed, tok_emb, emb_ext,
                                                       negent, logp);

    // hh_gates = h0 @ W_hh^T + b_ih + b_hh (step-invariant)
    gemm_part<<<dim3(H4_ / 64, 1, 4), 256, 0, stream>>>(enc_h0, W_hh, part, B_, H4_, H_);
    reduce_partials<<<(B_ * H4_ + 255) / 256, 256, 0, stream>>>(
        part, 4, b_ih, b_hh, hh_gates, B_ * H4_, H4_);

    // all_gates = emb_ext @ W_ih^T (no bias; biases live in hh_gates)
    gemm_part<<<dim3(H4_ / 64, 2, 1), 256, 0, stream>>>(emb_ext, W_ih, all_gates,
                                                        128, H4_, E_);

    // enc_t = encoder_outputs @ enc_W^T + enc_b (after part consumed)
    gemm_bt_128<<<dim3(H_ / 128, (S_ * B_) / 128), 256, 0, stream>>>(
        enc_out, enc_W, enc_b, enc_t, S_ * B_, H_, H_);

    for (int t = 0; t < T_; ++t) {
        const float* gsrc = (t == 0) ? (all_gates + (size_t)64 * H4_) : gates_sel;
        const size_t strideB = (t == 0) ? 0 : (size_t)H4_;
        lstm_dec_k<<<dim3(16, 4, 4), 256, 0, stream>>>(gsrc, strideB, hh_gates, enc_c0,
                                                       dec_W, out_h, dec_part);
        score_k<<<512, 256, 0, stream>>>(enc_t, dec_part, dec_b, attn_W, attn_b, lens, scores);
        smax_out_k<<<64, 256, 0, stream>>>(scores, enc_out, out_h, out_W, out_b,
                                           all_gates, lens, gates_sel, negent, logp, out, t);
    }
}

// Round 15
// 1663.290 us; speedup vs baseline: 1.5143x; 1.0733x over previous
//
#include <hip/hip_runtime.h>

#define S_ 160
#define B_ 64
#define H_ 1024
#define E_ 512
#define V_ 64
#define T_ 16
#define H4_ 4096

__device__ __forceinline__ float sigm(float x) { return 1.f / (1.f + expf(-x)); }

// ---------------------------------------------------------------------------
// enc_t = enc_out @ enc_W^T + enc_b.  128x128 tile, BK=16, 512 threads
// (8 waves -> 20 waves/CU vs 10 at 256 thr), 4x8 acc/thread, fragments
// split at stride 64 (2-way LDS bank aliases = free).
// ---------------------------------------------------------------------------
__global__ __launch_bounds__(512) void gemm_bt_128(
    const float* __restrict__ A, const float* __restrict__ Bm,
    const float* __restrict__ bias, float* __restrict__ Cd,
    int M, int N, int K)
{
    __shared__ float As[16][132];
    __shared__ float Bs[16][132];
    const int bn = blockIdx.x, bm = blockIdx.y;
    const int tid = threadIdx.x;
    const int lr = tid >> 2, lk = (tid & 3) * 4;     // staging: row, k-quad
    const int cx4 = (tid & 15) * 4, ry4 = (tid >> 4) * 4;  // compute mapping
    const float* Ap = A + (size_t)(bm * 128 + lr) * K + lk;
    const float* Bp = Bm + (size_t)(bn * 128 + lr) * K + lk;
    float acc[4][8] = {};
    for (int k0 = 0; k0 < K; k0 += 16) {
        float4 av = *(const float4*)(Ap + k0);
        float4 bv = *(const float4*)(Bp + k0);
        __syncthreads();
        As[lk + 0][lr] = av.x; As[lk + 1][lr] = av.y;
        As[lk + 2][lr] = av.z; As[lk + 3][lr] = av.w;
        Bs[lk + 0][lr] = bv.x; Bs[lk + 1][lr] = bv.y;
        Bs[lk + 2][lr] = bv.z; Bs[lk + 3][lr] = bv.w;
        __syncthreads();
#pragma unroll
        for (int kk = 0; kk < 16; ++kk) {
            float a[4], b[8];
            *(float4*)(a)     = *(const float4*)&As[kk][ry4];
            *(float4*)(b)     = *(const float4*)&Bs[kk][cx4];
            *(float4*)(b + 4) = *(const float4*)&Bs[kk][64 + cx4];
#pragma unroll
            for (int i = 0; i < 4; ++i)
#pragma unroll
                for (int j = 0; j < 8; ++j) acc[i][j] = fmaf(a[i], b[j], acc[i][j]);
        }
    }
#pragma unroll
    for (int i = 0; i < 4; ++i) {
        int row = bm * 128 + ry4 + i;
#pragma unroll
        for (int j = 0; j < 8; ++j) {
            int col = bn * 128 + ((j < 4) ? (cx4 + j) : (64 + cx4 + j - 4));
            Cd[(size_t)row * N + col] = acc[i][j] + bias[col];
        }
    }
}

// 64x64 tile GEMM helper (BK=16). Arow/Brow already offset by (lr*ld + lc).
__device__ __forceinline__ void tile64(const float* __restrict__ Arow,
                                       const float* __restrict__ Brow,
                                       int K, float acc[4][4],
                                       float* __restrict__ As,
                                       float* __restrict__ Bs)
{
    const int tid = threadIdx.x;
    const int lr = tid >> 2, lc = (tid & 3) << 2;
    const int tx = tid & 15, ty = tid >> 4;
    for (int k0 = 0; k0 < K; k0 += 16) {
        float4 av = *(const float4*)(Arow + k0);
        float4 bv = *(const float4*)(Brow + k0);
        __syncthreads();
        As[lr * 17 + lc + 0] = av.x; As[lr * 17 + lc + 1] = av.y;
        As[lr * 17 + lc + 2] = av.z; As[lr * 17 + lc + 3] = av.w;
        Bs[lr * 17 + lc + 0] = bv.x; Bs[lr * 17 + lc + 1] = bv.y;
        Bs[lr * 17 + lc + 2] = bv.z; Bs[lr * 17 + lc + 3] = bv.w;
        __syncthreads();
#pragma unroll
        for (int kk = 0; kk < 16; ++kk) {
            float a[4], b[4];
#pragma unroll
            for (int i = 0; i < 4; ++i) a[i] = As[(ty * 4 + i) * 17 + kk];
#pragma unroll
            for (int j = 0; j < 4; ++j) b[j] = Bs[(tx * 4 + j) * 17 + kk];
#pragma unroll
            for (int i = 0; i < 4; ++i)
#pragma unroll
                for (int j = 0; j < 4; ++j) acc[i][j] = fmaf(a[i], b[j], acc[i][j]);
        }
    }
    __syncthreads();
}

// Split-K partials: Cpart[kz][M][N] (validated). KS==1 -> plain GEMM to Cpart.
__global__ __launch_bounds__(256) void gemm_part(
    const float* __restrict__ A, const float* __restrict__ Bm,
    float* __restrict__ Cpart, int M, int N, int K)
{
    __shared__ float smem[2176];
    const int bn = blockIdx.x, bm = blockIdx.y, kz = blockIdx.z, KS = gridDim.z;
    const int tid = threadIdx.x;
    const int lr = tid >> 2, lc = (tid & 3) << 2;
    const int tx = tid & 15, ty = tid >> 4;
    const int kLen = K / KS, k0base = kz * kLen;
    float acc[4][4] = {};
    tile64(A + (size_t)(bm * 64 + lr) * K + k0base + lc,
           Bm + (size_t)(bn * 64 + lr) * K + k0base + lc,
           kLen, acc, smem, smem + 1088);
    float* Cp = Cpart + (size_t)kz * M * N;
#pragma unroll
    for (int i = 0; i < 4; ++i) {
        int row = bm * 64 + ty * 4 + i;
#pragma unroll
        for (int j = 0; j < 4; ++j)
            Cp[(size_t)row * N + bn * 64 + tx * 4 + j] = acc[i][j];
    }
}

__global__ void reduce_partials(const float* __restrict__ Cpart, int KS,
                                const float* __restrict__ bias,
                                const float* __restrict__ bias2,
                                float* __restrict__ C, int MN, int N)
{
    int idx = blockIdx.x * 256 + threadIdx.x;
    if (idx >= MN) return;
    float v = 0.f;
    for (int z = 0; z < KS; ++z) v += Cpart[(size_t)z * MN + idx];
    int col = idx % N;
    if (bias)  v += bias[col];
    if (bias2) v += bias2[col];
    C[idx] = v;
}

// Build emb_ext (rows 0..63 = embed, row 64 = tok_emb, 65..127 = 0);
// zero negent/logp accumulators.
__global__ void init_k(const float* __restrict__ embed, const float* __restrict__ tok_emb,
                       float* __restrict__ emb_ext,
                       float* __restrict__ negent, float* __restrict__ logp)
{
    int i = blockIdx.x * 256 + threadIdx.x;
    if (i < 128 * E_) {
        int r = i >> 9, c = i & (E_ - 1);
        emb_ext[i] = (r < 64) ? embed[r * E_ + c] : ((r == 64) ? tok_emb[c] : 0.f);
    }
    if (i < B_) { negent[i] = 0.f; logp[i] = 0.f; }
}

// ---------------------------------------------------------------------------
// Elementwise LSTM from gathered gate rows. t==0: SOS row (stride 0).
// 256 blocks x 256 threads; 1 cell/thread. (validated round 12)
// ---------------------------------------------------------------------------
__global__ __launch_bounds__(256) void lstm_gather_k(
    const float* __restrict__ gsrc, size_t strideB,
    const float* __restrict__ hh_gates, const float* __restrict__ enc_c0,
    float* __restrict__ out_h)
{
    int idx = blockIdx.x * 256 + threadIdx.x;   // B*H
    int b = idx >> 10, h = idx & (H_ - 1);
    const float* ag = gsrc + (size_t)b * strideB;
    const float* hg = hh_gates + (size_t)b * H4_;
    float gi = ag[h]           + hg[h];
    float gf = ag[H_ + h]      + hg[H_ + h];
    float gg = ag[2 * H_ + h]  + hg[2 * H_ + h];
    float go = ag[3 * H_ + h]  + hg[3 * H_ + h];
    float cc = sigm(gf) * enc_c0[idx] + sigm(gi) * tanhf(gg);
    out_h[idx] = sigm(go) * tanhf(cc);
}

// ---------------------------------------------------------------------------
// Attention scores: 512 blocks x 4 waves = 2048 waves; wave (b, sg) does 5 s.
// dec partial-sum (KS=4) + dec_b folded in registers. (validated round 8)
// ---------------------------------------------------------------------------
__global__ __launch_bounds__(256) void score_k(
    const float* __restrict__ enc_t, const float* __restrict__ dec_part,
    const float* __restrict__ dec_b, const float* __restrict__ attn_W,
    const float* __restrict__ attn_b, const int* __restrict__ lens,
    float* __restrict__ scores)
{
    const int lane = threadIdx.x & 63;
    const int gw = blockIdx.x * 4 + (threadIdx.x >> 6);   // 0..2047
    const int b = gw >> 5, sg = gw & 31;                  // 32 waves/b, 5 s each
    float dec_r[16], aw_r[16];
#pragma unroll
    for (int it = 0; it < 16; ++it) {
        int h = lane + it * 64;
        dec_r[it] = dec_part[(size_t)b * H_ + h]
                  + dec_part[(size_t)(B_ + b) * H_ + h]
                  + dec_part[(size_t)(2 * B_ + b) * H_ + h]
                  + dec_part[(size_t)(3 * B_ + b) * H_ + h]
                  + dec_b[h];
        aw_r[it] = attn_W[h];
    }
    const int len = lens[b];
    const float ab = attn_b[0];
    for (int s = sg * 5; s < sg * 5 + 5; ++s) {
        if (s >= len) { if (lane == 0) scores[b * S_ + s] = -1e9f; continue; }
        const float* ep = enc_t + ((size_t)s * B_ + b) * H_;
        float acc = 0.f;
#pragma unroll
        for (int it = 0; it < 16; ++it)
            acc += aw_r[it] * tanhf(ep[lane + it * 64] + dec_r[it]);
        for (int d = 32; d; d >>= 1) acc += __shfl_xor(acc, d);
        if (lane == 0) scores[b * S_ + s] = acc + ab;
    }
}

// ---------------------------------------------------------------------------
// Fused: softmax + attn-map out + context (float4, len-bounded) + logits +
// softmax/renorm + argmax + stats + VALUE-gather of next gate row.
// One block per b. (validated round 12/13)
// ---------------------------------------------------------------------------
__global__ __launch_bounds__(256) void smax_out_k(
    const float* __restrict__ scores, const float* __restrict__ enc_out,
    const float* __restrict__ out_h, const float* __restrict__ out_W,
    const float* __restrict__ out_b, const float* __restrict__ all_gates,
    const int* __restrict__ lens, float* __restrict__ gates_sel,
    float* __restrict__ negent_acc, float* __restrict__ logp_acc,
    float* __restrict__ out, int t)
{
    __shared__ float sc[S_];
    __shared__ float comb[2 * H_];
    __shared__ float lg[V_];
    __shared__ int tok_s;
    const int tid = threadIdx.x;
    const int b = blockIdx.x;
    const int lane = tid & 63, wv = tid >> 6;
    if (wv == 0) {
        float m = -1e30f;
        for (int s = lane; s < S_; s += 64) {
            float v = scores[b * S_ + s]; sc[s] = v; m = fmaxf(m, v);
        }
        for (int d = 32; d; d >>= 1) m = fmaxf(m, __shfl_xor(m, d));
        float sum = 0.f;
        for (int s = lane; s < S_; s += 64) {
            float e = expf(sc[s] - m); sc[s] = e; sum += e;
        }
        for (int d = 32; d; d >>= 1) sum += __shfl_xor(sum, d);
        float inv = 1.f / sum;
        for (int s = lane; s < S_; s += 64) {
            float pr = sc[s] * inv; sc[s] = pr;
            out[T_ * B_ + ((size_t)b * T_ + t) * S_ + s] = pr;
        }
    }
    __syncthreads();
    {   // context: 4 h per thread, float4, 4-way ILP, bounded by len
        const int len4 = (lens[b] + 3) & ~3;
        const float* base = enc_out + (size_t)b * H_ + tid * 4;
        float4 ac0 = {0,0,0,0}, ac1 = {0,0,0,0}, ac2 = {0,0,0,0}, ac3 = {0,0,0,0};
        for (int s = 0; s < len4; s += 4) {
            float4 e0 = *(const float4*)(base + (size_t)(s    ) * B_ * H_);
            float4 e1 = *(const float4*)(base + (size_t)(s + 1) * B_ * H_);
            float4 e2 = *(const float4*)(base + (size_t)(s + 2) * B_ * H_);
            float4 e3 = *(const float4*)(base + (size_t)(s + 3) * B_ * H_);
            float p0 = sc[s], p1 = sc[s + 1], p2 = sc[s + 2], p3 = sc[s + 3];
            ac0.x = fmaf(p0, e0.x, ac0.x); ac0.y = fmaf(p0, e0.y, ac0.y);
            ac0.z = fmaf(p0, e0.z, ac0.z); ac0.w = fmaf(p0, e0.w, ac0.w);
            ac1.x = fmaf(p1, e1.x, ac1.x); ac1.y = fmaf(p1, e1.y, ac1.y);
            ac1.z = fmaf(p1, e1.z, ac1.z); ac1.w = fmaf(p1, e1.w, ac1.w);
            ac2.x = fmaf(p2, e2.x, ac2.x); ac2.y = fmaf(p2, e2.y, ac2.y);
            ac2.z = fmaf(p2, e2.z, ac2.z); ac2.w = fmaf(p2, e2.w, ac2.w);
            ac3.x = fmaf(p3, e3.x, ac3.x); ac3.y = fmaf(p3, e3.y, ac3.y);
            ac3.z = fmaf(p3, e3.z, ac3.z); ac3.w = fmaf(p3, e3.w, ac3.w);
        }
        comb[tid * 4 + 0] = ac0.x + ac1.x + ac2.x + ac3.x;
        comb[tid * 4 + 1] = ac0.y + ac1.y + ac2.y + ac3.y;
        comb[tid * 4 + 2] = ac0.z + ac1.z + ac2.z + ac3.z;
        comb[tid * 4 + 3] = ac0.w + ac1.w + ac2.w + ac3.w;
    }
    for (int i = tid; i < H_; i += 256) comb[H_ + i] = out_h[(size_t)b * H_ + i];
    __syncthreads();
    for (int v = wv * 16; v < wv * 16 + 16; ++v) {
        const float* w = out_W + (size_t)v * (2 * H_);
        float a0 = 0.f, a1 = 0.f;
#pragma unroll
        for (int j = 0; j < 32; j += 2) {
            a0 = fmaf(comb[lane + j * 64], w[lane + j * 64], a0);
            a1 = fmaf(comb[lane + (j + 1) * 64], w[lane + (j + 1) * 64], a1);
        }
        float acc = a0 + a1;
        for (int d = 32; d; d >>= 1) acc += __shfl_xor(acc, d);
        if (lane == 0) lg[v] = acc + out_b[v];
    }
    __syncthreads();
    if (wv == 0) {
        float x = lg[lane];
        float m = x;
        for (int d = 32; d; d >>= 1) m = fmaxf(m, __shfl_xor(m, d));
        float e = expf(x - m);
        float s = e;
        for (int d = 32; d; d >>= 1) s += __shfl_xor(s, d);
        float pr = e / s;
        float ps = pr;
        for (int d = 32; d; d >>= 1) ps += __shfl_xor(ps, d);
        pr = pr / ps;   // reference renormalizes
        float bv = pr; int bi = lane;
        for (int d = 32; d; d >>= 1) {
            float ov = __shfl_xor(bv, d); int oi = __shfl_xor(bi, d);
            if (ov > bv || (ov == bv && oi < bi)) { bv = ov; bi = oi; }
        }
        float ne = pr * logf(pr + 1e-6f);
        for (int d = 32; d; d >>= 1) ne += __shfl_xor(ne, d);
        float ptok = __shfl(pr, bi);
        if (lane == 0) {
            out[t * B_ + b] = (float)bi;
            float na = negent_acc[b] + ne;                negent_acc[b] = na;
            float la = logp_acc[b] + logf(ptok + 1e-6f);  logp_acc[b] = la;
            if (t == T_ - 1) {
                out[T_ * B_ + B_ * T_ * S_ + b] = na;
                out[T_ * B_ + B_ * T_ * S_ + B_ + b] = la;
            }
            tok_s = bi;
        }
    }
    __syncthreads();
    {   // value-gather: gates_sel[b] = all_gates[tok_s]  (4096 floats, float4)
        const int tk = tok_s;
        const float4* src = (const float4*)(all_gates + (size_t)tk * H4_);
        float4* dst = (float4*)(gates_sel + (size_t)b * H4_);
        for (int i = tid; i < H4_ / 4; i += 256) dst[i] = src[i];
    }
}

extern "C" void kernel_launch(void* const* d_in, const int* in_sizes, int n_in,
                              void* d_out, int out_size, void* d_ws, size_t ws_size,
                              hipStream_t stream) {
    const float* enc_h0  = (const float*)d_in[0];
    const float* enc_c0  = (const float*)d_in[1];
    const float* enc_out = (const float*)d_in[2];
    const int*   lens    = (const int*)d_in[3];
    const float* tok_emb = (const float*)d_in[4];
    const float* embed   = (const float*)d_in[5];
    const float* W_ih    = (const float*)d_in[6];
    const float* W_hh    = (const float*)d_in[7];
    const float* b_ih    = (const float*)d_in[8];
    const float* b_hh    = (const float*)d_in[9];
    const float* out_W   = (const float*)d_in[10];
    const float* out_b   = (const float*)d_in[11];
    const float* enc_W   = (const float*)d_in[12];
    const float* enc_b   = (const float*)d_in[13];
    const float* dec_W   = (const float*)d_in[14];
    const float* dec_b   = (const float*)d_in[15];
    const float* attn_W  = (const float*)d_in[16];
    const float* attn_b  = (const float*)d_in[17];
    float* out = (float*)d_out;

    // ws layout (floats). part aliases enc_t (consumed before enc_t written).
    float* ws = (float*)d_ws;
    float* hh_gates  = ws;                         // 262144
    float* out_h     = hh_gates + B_ * H4_;        // 65536
    float* dec_part  = out_h + B_ * H_;            // 262144
    float* scores    = dec_part + 4 * B_ * H_;     // 10240
    float* negent    = scores + B_ * S_;           // 64
    float* logp      = negent + B_;                // 64
    float* gates_sel = logp + B_;                  // 262144 (B x 4H)
    float* emb_ext   = gates_sel + B_ * H4_;       // 65536 (128 x 512)
    float* all_gates = emb_ext + 128 * E_;         // 524288 (128 x 4096)
    float* enc_t     = all_gates + (size_t)128 * H4_;  // 10485760
    float* part      = enc_t;                      // alias: 4 x B x 4H
    // total = 11,937,920 floats = 47,751,680 B (ws_size known >= 49,152,512)
    if (ws_size < 47751680u) return;

    init_k<<<(128 * E_ + 255) / 256, 256, 0, stream>>>(embed, tok_emb, emb_ext,
                                                       negent, logp);

    // hh_gates = h0 @ W_hh^T + b_ih + b_hh (step-invariant)
    gemm_part<<<dim3(H4_ / 64, 1, 4), 256, 0, stream>>>(enc_h0, W_hh, part, B_, H4_, H_);
    reduce_partials<<<(B_ * H4_ + 255) / 256, 256, 0, stream>>>(
        part, 4, b_ih, b_hh, hh_gates, B_ * H4_, H4_);

    // all_gates = emb_ext @ W_ih^T (no bias; biases live in hh_gates)
    gemm_part<<<dim3(H4_ / 64, 2, 1), 256, 0, stream>>>(emb_ext, W_ih, all_gates,
                                                        128, H4_, E_);

    // enc_t = encoder_outputs @ enc_W^T + enc_b (after part consumed)
    gemm_bt_128<<<dim3(H_ / 128, (S_ * B_) / 128), 512, 0, stream>>>(
        enc_out, enc_W, enc_b, enc_t, S_ * B_, H_, H_);

    for (int t = 0; t < T_; ++t) {
        const float* gsrc = (t == 0) ? (all_gates + (size_t)64 * H4_) : gates_sel;
        const size_t strideB = (t == 0) ? 0 : (size_t)H4_;
        lstm_gather_k<<<(B_ * H_) / 256, 256, 0, stream>>>(gsrc, strideB, hh_gates,
                                                           enc_c0, out_h);
        gemm_part<<<dim3(H_ / 64, 1, 4), 256, 0, stream>>>(out_h, dec_W, dec_part, B_, H_, H_);
        score_k<<<512, 256, 0, stream>>>(enc_t, dec_part, dec_b, attn_W, attn_b, lens, scores);
        smax_out_k<<<64, 256, 0, stream>>>(scores, enc_out, out_h, out_W, out_b,
                                           all_gates, lens, gates_sel, negent, logp, out, t);
    }
}